// Round 5
// baseline (920.813 us; speedup 1.0000x reference)
//
#include <hip/hip_runtime.h>
#include <stdint.h>

#define B_ROWS 4096
#define N_ROWS 8192
#define D_DIM  1024
#define BK     64
#define TILE   256
#define NBLK   32                       // 8192 / 256 tiles per dim
#define NTRI   (NBLK * (NBLK + 1) / 2)  // 528 upper-triangular tiles

typedef __attribute__((ext_vector_type(8))) short bf16x8;
typedef __attribute__((ext_vector_type(4))) float f32x4;

// round-to-nearest-even f32 -> bf16
static __device__ __forceinline__ unsigned short f2bf(float f) {
  uint32_t u = __float_as_uint(f);
  u += 0x7fff + ((u >> 16) & 1);
  return (unsigned short)(u >> 16);
}

static __device__ __forceinline__ void async_copy16(const unsigned short* g, unsigned short* l) {
  __builtin_amdgcn_global_load_lds(
      (const __attribute__((address_space(1))) unsigned int*)g,
      (__attribute__((address_space(3))) unsigned int*)l, 16, 0, 0);
}

// One wave per row: L2-normalize, cast to bf16, zero rowsum (+ctr).
__global__ __launch_bounds__(256) void normalize_kernel(
    const float* __restrict__ f1, const float* __restrict__ f2,
    unsigned short* __restrict__ F, float* __restrict__ rowsum,
    unsigned int* __restrict__ ctr) {
  const int wv   = threadIdx.x >> 6;
  const int lane = threadIdx.x & 63;
  const int row  = blockIdx.x * 4 + wv;
  const float* src = (row < B_ROWS) ? (f1 + (size_t)row * D_DIM)
                                    : (f2 + (size_t)(row - B_ROWS) * D_DIM);
  float4 v[4];
  float ss = 0.0f;
#pragma unroll
  for (int r = 0; r < 4; ++r) {
    v[r] = ((const float4*)src)[lane + 64 * r];
    ss += v[r].x * v[r].x + v[r].y * v[r].y + v[r].z * v[r].z + v[r].w * v[r].w;
  }
#pragma unroll
  for (int m = 1; m < 64; m <<= 1) ss += __shfl_xor(ss, m, 64);
  const float invn = 1.0f / fmaxf(sqrtf(ss), 1e-12f);
  ushort4* dst = (ushort4*)(F + (size_t)row * D_DIM);
#pragma unroll
  for (int r = 0; r < 4; ++r) {
    ushort4 o;
    o.x = f2bf(v[r].x * invn); o.y = f2bf(v[r].y * invn);
    o.z = f2bf(v[r].z * invn); o.w = f2bf(v[r].w * invn);
    dst[lane + 64 * r] = o;
  }
  if (lane == 0) rowsum[row] = 0.0f;
  if (row == 0 && lane == 0) *ctr = 0u;
}

// Fused Gram-GEMM + exp-sum + fused finalize over the upper-triangular
// 256x256 tile grid. 512 threads = 8 waves; each wave owns a 64x128
// subtile (waveRow 0..3 x waveCol 0..1) as a 4x8 grid of 16x16x32 bf16
// MFMA. Single-buffered BK=64 (m97 structure: amortize the barrier with
// 64 MFMA/wave per iteration instead of fighting the vmcnt(0) drain).
// LDS 2x32KB -> 2 blocks/CU = 16 waves/CU resident.
// Chunk swizzle: 16B chunk lc holds row=lc>>3, col8=(lc&7)^(row&7);
// reader chunk = r*8 + (cbase ^ (r&7)), cbase=(kk>>3)+q.
__global__ __launch_bounds__(512, 4) void simloss_kernel(
    const unsigned short* __restrict__ F, float* __restrict__ rowsum,
    float* __restrict__ pos, unsigned int* __restrict__ ctr,
    float* __restrict__ out) {
  __shared__ unsigned short lA[TILE * BK];
  __shared__ unsigned short lB[TILE * BK];

  // XCD band swizzle: 528 = 8 * 66 -> each XCD gets a contiguous band.
  const int b    = (int)blockIdx.x;
  const int tile = (b & 7) * (NTRI / 8) + (b >> 3);

  // decode tile -> (bi, bj), bi <= bj
  int rem = tile;
  int bi = 0;
  while (rem >= NBLK - bi) { rem -= NBLK - bi; ++bi; }
  const int bj = bi + rem;

  const int tid  = threadIdx.x;
  const int lane = tid & 63;
  const int wv   = __builtin_amdgcn_readfirstlane(tid >> 6);
  const int waveRow = wv >> 1;   // 0..3
  const int waveCol = wv & 1;    // 0..1
  const int q   = lane >> 4;     // quad within wave
  const int l16 = lane & 15;

  const int iBase = bi * TILE;
  const int jBase = bj * TILE;
  const unsigned short* Abase = F + (size_t)iBase * D_DIM;
  const unsigned short* Bbase = F + (size_t)jBase * D_DIM;

  f32x4 acc[4][8];
#pragma unroll
  for (int a = 0; a < 4; ++a)
#pragma unroll
    for (int c = 0; c < 8; ++c) acc[a][c] = (f32x4){0.f, 0.f, 0.f, 0.f};

  // staging: 2048 16B-chunks per tile, 512 threads x 4 chunks
  int s_lc[4]; size_t s_go[4];
#pragma unroll
  for (int c4 = 0; c4 < 4; ++c4) {
    const int lc  = c4 * 512 + tid;
    const int row = lc >> 3;
    const int gc  = (lc & 7) ^ (row & 7);
    s_lc[c4] = lc;
    s_go[c4] = (size_t)row * D_DIM + gc * 8;
  }
  // reader chunk offsets (elements), fixed across iterations
  int rdA[4], rdB[8];
#pragma unroll
  for (int mi = 0; mi < 4; ++mi) {
    const int r = waveRow * 64 + mi * 16 + l16;
    rdA[mi] = (r * 8 + (q ^ (r & 7))) * 8;   // cbase=q substep handled below
  }
#pragma unroll
  for (int ni = 0; ni < 8; ++ni) {
    const int r = waveCol * 128 + ni * 16 + l16;
    rdB[ni] = (r * 8 + (q ^ (r & 7))) * 8;
  }

  for (int k0 = 0; k0 < D_DIM; k0 += BK) {
#pragma unroll
    for (int c4 = 0; c4 < 4; ++c4) {
      async_copy16(Abase + k0 + s_go[c4], &lA[s_lc[c4] * 8]);
      async_copy16(Bbase + k0 + s_go[c4], &lB[s_lc[c4] * 8]);
    }
    __syncthreads();

#pragma unroll
    for (int kk = 0; kk < BK; kk += 32) {
      // substep kk: cbase = (kk>>3)+q. rd* were computed with cbase=q;
      // XOR trick: (cbase ^ (r&7)) = ((q ^ (r&7)) ^ (kk>>3)) only when
      // (kk>>3) has no bits overlapping... kk=32 -> kk>>3 = 4; q in 0..3,
      // r&7 in 0..7: (4+q) differs from (q^4) -- need additive form, so
      // recompute chunk index per substep instead:
      bf16x8 af[4], bfr[8];
#pragma unroll
      for (int mi = 0; mi < 4; ++mi) {
        const int r = waveRow * 64 + mi * 16 + l16;
        const int ch = r * 8 + (((kk >> 3) + q) ^ (r & 7));
        af[mi] = *(const bf16x8*)&lA[ch * 8];
      }
#pragma unroll
      for (int ni = 0; ni < 8; ++ni) {
        const int r = waveCol * 128 + ni * 16 + l16;
        const int ch = r * 8 + (((kk >> 3) + q) ^ (r & 7));
        bfr[ni] = *(const bf16x8*)&lB[ch * 8];
      }
#pragma unroll
      for (int mi = 0; mi < 4; ++mi)
#pragma unroll
        for (int ni = 0; ni < 8; ++ni)
          acc[mi][ni] = __builtin_amdgcn_mfma_f32_16x16x32_bf16(
              af[mi], bfr[ni], acc[mi][ni], 0, 0, 0);
    }
    __syncthreads();
  }

  // ---- epilogue ----
  const bool offdiag = (bi != bj);
  float colAcc[8] = {0.f, 0.f, 0.f, 0.f, 0.f, 0.f, 0.f, 0.f};

#pragma unroll
  for (int mi = 0; mi < 4; ++mi) {
#pragma unroll
    for (int reg = 0; reg < 4; ++reg) {
      const int i = iBase + waveRow * 64 + mi * 16 + q * 4 + reg;
      float s = 0.0f;
#pragma unroll
      for (int ni = 0; ni < 8; ++ni) {
        const int j = jBase + waveCol * 128 + ni * 16 + l16;
        const float sim = acc[mi][ni][reg] * 10.0f;
        const float e = (j == i) ? 0.0f : __expf(sim - 10.0f);
        s += e;
        colAcc[ni] += e;
        if (i < B_ROWS && j == i + B_ROWS) pos[i] = sim;
      }
#pragma unroll
      for (int m = 1; m < 16; m <<= 1) s += __shfl_xor(s, m, 64);
      if (l16 == 0) atomicAdd(&rowsum[i], s);
    }
  }

  if (offdiag) {
#pragma unroll
    for (int ni = 0; ni < 8; ++ni) {
      float c = colAcc[ni];
#pragma unroll
      for (int m = 16; m < 64; m <<= 1) c += __shfl_xor(c, m, 64);
      if (q == 0) {
        const int j = jBase + waveCol * 128 + ni * 16 + l16;
        atomicAdd(&rowsum[j], c);
      }
    }
  }

  // ---- fused finalize: last block computes the loss ----
  __syncthreads();
  __shared__ unsigned int lastFlag;
  if (tid == 0) {
    __threadfence();
    const unsigned int old = atomicAdd(ctr, 1u);
    lastFlag = (old == (unsigned int)(NTRI - 1)) ? 1u : 0u;
  }
  __syncthreads();
  if (lastFlag) {
    __threadfence();
    float a = 0.0f;
    for (int i = tid; i < N_ROWS; i += 512)
      a += __logf(rowsum[i]) + 10.0f - pos[i & (B_ROWS - 1)];
#pragma unroll
    for (int m = 1; m < 64; m <<= 1) a += __shfl_xor(a, m, 64);
    __shared__ float red[8];
    if ((tid & 63) == 0) red[tid >> 6] = a;
    __syncthreads();
    if (tid == 0) {
      float t = 0.0f;
#pragma unroll
      for (int w = 0; w < 8; ++w) t += red[w];
      out[0] = t * (1.0f / N_ROWS);
    }
  }
}

extern "C" void kernel_launch(void* const* d_in, const int* in_sizes, int n_in,
                              void* d_out, int out_size, void* d_ws, size_t ws_size,
                              hipStream_t stream) {
  const float* f1 = (const float*)d_in[0];
  const float* f2 = (const float*)d_in[1];
  unsigned short* F = (unsigned short*)d_ws;                          // 16 MiB bf16 normalized features
  float* rowsum = (float*)((char*)d_ws + (size_t)N_ROWS * D_DIM * 2); // 32 KiB
  float* pos    = rowsum + N_ROWS;                                    // 16 KiB (i < B_ROWS)
  unsigned int* ctr = (unsigned int*)(pos + B_ROWS);                  // 4 B completion counter
  float* out    = (float*)d_out;

  hipLaunchKernelGGL(normalize_kernel, dim3(N_ROWS / 4), dim3(256), 0, stream,
                     f1, f2, F, rowsum, ctr);
  hipLaunchKernelGGL(simloss_kernel, dim3(NTRI), dim3(512), 0, stream,
                     F, rowsum, pos, ctr, out);
}

// Round 6
// 213.304 us; speedup vs baseline: 4.3169x; 4.3169x over previous
//
#include <hip/hip_runtime.h>
#include <stdint.h>

#define B_ROWS 4096
#define N_ROWS 8192
#define D_DIM  1024                     // elements per row (= bytes in fp8)
#define BKB    128                      // k-elements (=bytes) staged per iter
#define NBLK   64                       // 8192 / 128 tiles per dim
#define NTRI   (NBLK * (NBLK + 1) / 2)  // 2080 upper-triangular tiles

typedef __attribute__((ext_vector_type(2))) long longx2;
typedef __attribute__((ext_vector_type(4))) float f32x4;

static __device__ __forceinline__ void async_copy16(const unsigned char* g, unsigned char* l) {
  __builtin_amdgcn_global_load_lds(
      (const __attribute__((address_space(1))) unsigned int*)g,
      (__attribute__((address_space(3))) unsigned int*)l, 16, 0, 0);
}

// One wave per row: L2-normalize, cast to fp8 e4m3 (native v_cvt_pk_fp8_f32),
// zero rowsum (+ctr). Each lane handles 16 CONTIGUOUS elements -> one uint4
// (16 fp8 bytes) store.
__global__ __launch_bounds__(256) void normalize_kernel(
    const float* __restrict__ f1, const float* __restrict__ f2,
    unsigned char* __restrict__ F, float* __restrict__ rowsum,
    unsigned int* __restrict__ ctr) {
  const int wv   = threadIdx.x >> 6;
  const int lane = threadIdx.x & 63;
  const int row  = blockIdx.x * 4 + wv;
  const float* src = (row < B_ROWS) ? (f1 + (size_t)row * D_DIM)
                                    : (f2 + (size_t)(row - B_ROWS) * D_DIM);
  const float4* s4 = (const float4*)src;
  float4 v[4];
  float ss = 0.0f;
#pragma unroll
  for (int r = 0; r < 4; ++r) {
    v[r] = s4[lane * 4 + r];            // elements [lane*16 + r*4, +4)
    ss += v[r].x * v[r].x + v[r].y * v[r].y + v[r].z * v[r].z + v[r].w * v[r].w;
  }
#pragma unroll
  for (int m = 1; m < 64; m <<= 1) ss += __shfl_xor(ss, m, 64);
  const float invn = 1.0f / fmaxf(sqrtf(ss), 1e-12f);
  uint32_t p[4];
#pragma unroll
  for (int r = 0; r < 4; ++r) {
    uint32_t lo = __builtin_amdgcn_cvt_pk_fp8_f32(v[r].x * invn, v[r].y * invn, 0, false);
    p[r] = __builtin_amdgcn_cvt_pk_fp8_f32(v[r].z * invn, v[r].w * invn, lo, true);
  }
  uint4 o; o.x = p[0]; o.y = p[1]; o.z = p[2]; o.w = p[3];
  ((uint4*)(F + (size_t)row * D_DIM))[lane] = o;
  if (lane == 0) rowsum[row] = 0.0f;
  if (row == 0 && lane == 0) *ctr = 0u;
}

// Fused Gram-GEMM (fp8 e4m3) + exp-sum epilogue + fused finalize over the
// upper-triangular 128x128 tile grid. 256 threads = 4 waves, each wave a
// 64x64 subtile as 4x4 grid of 16x16x32 fp8 MFMA (fp8 = bf16 rate, but
// HALF the staged bytes and LDS traffic -> attacks the staging-BW bound).
// BK=128 k-elements = 128 B/row = 8 x 16B chunks, same XOR chunk swizzle as
// the 0-conflict bf16 layout: chunk (r,c) stored at r*8 + (c ^ (r&7)).
// Each lane reads one contiguous 32 B [q*32, +32) of its row as 2x
// ds_read_b128 (iteration-invariant addresses); k-reorder: substep s uses
// long s of the 4-long fragment (dot is k-order invariant).
__global__ __launch_bounds__(256) void simloss_kernel(
    const unsigned char* __restrict__ F, float* __restrict__ rowsum,
    float* __restrict__ pos, unsigned int* __restrict__ ctr,
    float* __restrict__ out) {
  __shared__ unsigned char lA[128 * BKB];   // 16 KB
  __shared__ unsigned char lB[128 * BKB];   // 16 KB

  // XCD band swizzle: 2080 = 8 * 260 -> contiguous triangle band per XCD.
  const int b    = (int)blockIdx.x;
  const int tile = (b & 7) * (NTRI / 8) + (b >> 3);

  int rem = tile;
  int bi = 0;
  while (rem >= NBLK - bi) { rem -= NBLK - bi; ++bi; }
  const int bj = bi + rem;

  const int tid  = threadIdx.x;
  const int lane = tid & 63;
  const int wv   = __builtin_amdgcn_readfirstlane(tid >> 6);
  const int waveRow = wv >> 1;
  const int waveCol = wv & 1;
  const int q   = lane >> 4;
  const int l16 = lane & 15;

  const int iBase = bi * 128;
  const int jBase = bj * 128;
  const unsigned char* Abase = F + (size_t)iBase * D_DIM;
  const unsigned char* Bbase = F + (size_t)jBase * D_DIM;

  f32x4 acc[4][4];
#pragma unroll
  for (int a = 0; a < 4; ++a)
#pragma unroll
    for (int c = 0; c < 4; ++c) acc[a][c] = (f32x4){0.f, 0.f, 0.f, 0.f};

  // staging: 1024 chunks per tile, 256 threads x 4 chunks (for A and B each)
  int s_lc[4]; int s_go[4];
#pragma unroll
  for (int c4 = 0; c4 < 4; ++c4) {
    const int lc = c4 * 256 + tid;
    const int r  = lc >> 3;
    const int gc = (lc & 7) ^ (r & 7);
    s_lc[c4] = lc;
    s_go[c4] = r * D_DIM + gc * 16;
  }
  // reader byte addresses (iteration-invariant)
  int rdA[4][2], rdB[4][2];
#pragma unroll
  for (int mi = 0; mi < 4; ++mi) {
    const int r = waveRow * 64 + mi * 16 + l16;
    rdA[mi][0] = (r * 8 + ((2 * q) ^ (r & 7))) * 16;
    rdA[mi][1] = (r * 8 + ((2 * q + 1) ^ (r & 7))) * 16;
  }
#pragma unroll
  for (int ni = 0; ni < 4; ++ni) {
    const int r = waveCol * 64 + ni * 16 + l16;
    rdB[ni][0] = (r * 8 + ((2 * q) ^ (r & 7))) * 16;
    rdB[ni][1] = (r * 8 + ((2 * q + 1) ^ (r & 7))) * 16;
  }

  for (int k0 = 0; k0 < D_DIM; k0 += BKB) {
#pragma unroll
    for (int c4 = 0; c4 < 4; ++c4) {
      async_copy16(Abase + k0 + s_go[c4], &lA[s_lc[c4] * 16]);
      async_copy16(Bbase + k0 + s_go[c4], &lB[s_lc[c4] * 16]);
    }
    __syncthreads();

    longx2 a01[4], a23[4], b01[4], b23[4];
#pragma unroll
    for (int mi = 0; mi < 4; ++mi) {
      a01[mi] = *(const longx2*)&lA[rdA[mi][0]];   // substeps 0,1
      a23[mi] = *(const longx2*)&lA[rdA[mi][1]];   // substeps 2,3
    }
#pragma unroll
    for (int ni = 0; ni < 4; ++ni) {
      b01[ni] = *(const longx2*)&lB[rdB[ni][0]];
      b23[ni] = *(const longx2*)&lB[rdB[ni][1]];
    }
#pragma unroll
    for (int mi = 0; mi < 4; ++mi)
#pragma unroll
      for (int ni = 0; ni < 4; ++ni)
        acc[mi][ni] = __builtin_amdgcn_mfma_f32_16x16x32_fp8_fp8(
            a01[mi].x, b01[ni].x, acc[mi][ni], 0, 0, 0);
#pragma unroll
    for (int mi = 0; mi < 4; ++mi)
#pragma unroll
      for (int ni = 0; ni < 4; ++ni)
        acc[mi][ni] = __builtin_amdgcn_mfma_f32_16x16x32_fp8_fp8(
            a01[mi].y, b01[ni].y, acc[mi][ni], 0, 0, 0);
#pragma unroll
    for (int mi = 0; mi < 4; ++mi)
#pragma unroll
      for (int ni = 0; ni < 4; ++ni)
        acc[mi][ni] = __builtin_amdgcn_mfma_f32_16x16x32_fp8_fp8(
            a23[mi].x, b23[ni].x, acc[mi][ni], 0, 0, 0);
#pragma unroll
    for (int mi = 0; mi < 4; ++mi)
#pragma unroll
      for (int ni = 0; ni < 4; ++ni)
        acc[mi][ni] = __builtin_amdgcn_mfma_f32_16x16x32_fp8_fp8(
            a23[mi].y, b23[ni].y, acc[mi][ni], 0, 0, 0);
    __syncthreads();
  }

  // ---- epilogue: sim = 10*dot; e = exp(sim-10) excluding diagonal.
  // Row-reduce -> rowsum[i]; off-diag tiles also column-reduce -> rowsum[j].
  const bool offdiag = (bi != bj);
  float colAcc[4] = {0.f, 0.f, 0.f, 0.f};

#pragma unroll
  for (int mi = 0; mi < 4; ++mi) {
#pragma unroll
    for (int reg = 0; reg < 4; ++reg) {
      const int i = iBase + waveRow * 64 + mi * 16 + q * 4 + reg;
      float s = 0.0f;
#pragma unroll
      for (int ni = 0; ni < 4; ++ni) {
        const int j = jBase + waveCol * 64 + ni * 16 + l16;
        const float sim = acc[mi][ni][reg] * 10.0f;
        const float e = (j == i) ? 0.0f : __expf(sim - 10.0f);
        s += e;
        colAcc[ni] += e;
        if (i < B_ROWS && j == i + B_ROWS) pos[i] = sim;
      }
#pragma unroll
      for (int m = 1; m < 16; m <<= 1) s += __shfl_xor(s, m, 64);
      if (l16 == 0) atomicAdd(&rowsum[i], s);
    }
  }

  if (offdiag) {
#pragma unroll
    for (int ni = 0; ni < 4; ++ni) {
      float c = colAcc[ni];
#pragma unroll
      for (int m = 16; m < 64; m <<= 1) c += __shfl_xor(c, m, 64);
      if (q == 0) {
        const int j = jBase + waveCol * 64 + ni * 16 + l16;
        atomicAdd(&rowsum[j], c);
      }
    }
  }

  // ---- fused finalize: last block computes the loss ----
  __syncthreads();
  __shared__ unsigned int lastFlag;
  if (tid == 0) {
    __threadfence();
    const unsigned int old = atomicAdd(ctr, 1u);
    lastFlag = (old == (unsigned int)(NTRI - 1)) ? 1u : 0u;
  }
  __syncthreads();
  if (lastFlag) {
    __threadfence();
    float a = 0.0f;
    for (int i = tid; i < N_ROWS; i += 256)
      a += __logf(rowsum[i]) + 10.0f - pos[i & (B_ROWS - 1)];
#pragma unroll
    for (int m = 1; m < 64; m <<= 1) a += __shfl_xor(a, m, 64);
    __shared__ float red[4];
    if ((tid & 63) == 0) red[tid >> 6] = a;
    __syncthreads();
    if (tid == 0) out[0] = (red[0] + red[1] + red[2] + red[3]) * (1.0f / N_ROWS);
  }
}

extern "C" void kernel_launch(void* const* d_in, const int* in_sizes, int n_in,
                              void* d_out, int out_size, void* d_ws, size_t ws_size,
                              hipStream_t stream) {
  const float* f1 = (const float*)d_in[0];
  const float* f2 = (const float*)d_in[1];
  unsigned char* F = (unsigned char*)d_ws;                        // 8 MiB fp8 normalized features
  float* rowsum = (float*)((char*)d_ws + (size_t)N_ROWS * D_DIM); // 32 KiB
  float* pos    = rowsum + N_ROWS;                                // 16 KiB (i < B_ROWS)
  unsigned int* ctr = (unsigned int*)(pos + B_ROWS);              // 4 B completion counter
  float* out    = (float*)d_out;

  hipLaunchKernelGGL(normalize_kernel, dim3(N_ROWS / 4), dim3(256), 0, stream,
                     f1, f2, F, rowsum, ctr);
  hipLaunchKernelGGL(simloss_kernel, dim3(NTRI), dim3(256), 0, stream,
                     F, rowsum, pos, ctr, out);
}